// Round 20
// baseline (159.993 us; speedup 1.0000x reference)
//
#include <hip/hip_runtime.h>

#define GLOBAL_AS __attribute__((address_space(1)))
#define LDS_AS    __attribute__((address_space(3)))

typedef int   i32x4  __attribute__((ext_vector_type(4)));
typedef int   i32x8  __attribute__((ext_vector_type(8)));
typedef float f32x4  __attribute__((ext_vector_type(4)));

// ---------- fp4 e2m1 encode: values {0,.5,1,1.5,2,3,4,6}, round-to-nearest ----------
__device__ __forceinline__ unsigned int fp4_nib(float v) {
    float a = fabsf(v);
    unsigned int m;
    if      (a < 0.25f) m = 0;
    else if (a < 0.75f) m = 1;
    else if (a < 1.25f) m = 2;
    else if (a < 1.75f) m = 3;
    else if (a < 2.5f)  m = 4;
    else if (a < 3.5f)  m = 5;
    else if (a < 5.0f)  m = 6;
    else                m = 7;
    return m | (v < 0.0f ? 8u : 0u);
}

// ---------- kernel 1: fused L2 normalize -> fp4 of (x * 32 / ||row||) ----------
// out rows: 768 elts = 384 B (2 elts/byte, elt 2i = low nibble).
__global__ __launch_bounds__(256) void l2norm_fp4_kernel(const float* __restrict__ audio,
                                                         const float* __restrict__ visual,
                                                         unsigned char* __restrict__ out) {
    const int gw = blockIdx.x * 4 + (threadIdx.x >> 6);  // global row 0..24575
    const int l  = threadIdx.x & 63;
    const float* src = (gw < 16384) ? (audio + (size_t)gw * 768)
                                    : (visual + ((size_t)gw - 16384) * 768);
    const float4* p = (const float4*)src;
    float4 a = p[l], b = p[l + 64], c = p[l + 128];
    float ss = a.x * a.x + a.y * a.y + a.z * a.z + a.w * a.w
             + b.x * b.x + b.y * b.y + b.z * b.z + b.w * b.w
             + c.x * c.x + c.y * c.y + c.z * c.z + c.w * c.w;
#pragma unroll
    for (int m = 1; m < 64; m <<= 1) ss += __shfl_xor(ss, m, 64);
    const float s = 32.0f / fmaxf(sqrtf(ss), 1e-12f);
    unsigned short* o = (unsigned short*)(out + (size_t)gw * 384);
    unsigned short u0 = (unsigned short)(fp4_nib(a.x * s) | (fp4_nib(a.y * s) << 4) |
                                         (fp4_nib(a.z * s) << 8) | (fp4_nib(a.w * s) << 12));
    unsigned short u1 = (unsigned short)(fp4_nib(b.x * s) | (fp4_nib(b.y * s) << 4) |
                                         (fp4_nib(b.z * s) << 8) | (fp4_nib(b.w * s) << 12));
    unsigned short u2 = (unsigned short)(fp4_nib(c.x * s) | (fp4_nib(c.y * s) << 4) |
                                         (fp4_nib(c.z * s) << 8) | (fp4_nib(c.w * s) << 12));
    o[l] = u0; o[l + 64] = u1; o[l + 128] = u2;
}

// ---------- kernel 2: 128x64-tile MX-fp4 GEMM, 2-wave blocks, counted-vmcnt dbuf ---
// R18's verified schedule with the block shrunk 256->128 threads (2 waves):
//  - tile 128 audio rows x 64 visual cols (quarter clip); wave tile 64x64 as before
//  - LDS 2 x 12 KiB -> 6 blocks/CU = 6 desynchronized streams (vs 3): the m114
//    cross-block overlap this structure relies on; barriers sync 2 waves not 4
//  - each wave owns its 64 output rows -> epilogue writes DIRECT to global
//    (no pm LDS round-trip, no extra barriers)
// Schedule per K-tile kt (buf=kt&1): vmcnt(6) [kt landed, kt+1's 6 in flight] ->
// raw s_barrier -> 8 ds_reads + 16 MFMA -> raw s_barrier -> STAGE(buf, kt+2).
// No vmcnt(0) drain in the main loop; stage->use distance = 2 iterations.
// Frag-slot layout (per 12 KB buf): A @0: granule g = fi*64 + lane (fi 0..7)
// holds (row = fi*16 + (lane&15), K-bytes ((lane>>4)&3)*16 .. +15); B @8192:
// fi 0..3 same map over the 64 V-rows. Read = ONE lane-linear ds_read_b128/frag
// (0 conflicts). Stage dest linear: A q*2048+tid*16 (q 0..3), B 8192+q*2048 (q 0..1)
// -> source row = 32q + 16*(tid>>6) + (tid&15), kb = ((tid>>4)&3)*16; each wave
// covers 16 rows x contiguous 64 B = 16 full lines (coalesced).
// MFMA: cbsz=4, blgp=4 (FP4), payload regs [0:3] (upper half undef, R19-verified).
// NOTE: min-waves stays 3 (cap 168 >> ~128 demand incl. AGPR acc; R5/R15 spill lesson).

__device__ __forceinline__ i32x8 rd_frag4(const char* p) {
    i32x4 d = *(const i32x4*)(p);
    return __builtin_shufflevector(d, d, 0, 1, 2, 3, -1, -1, -1, -1);
}

#define STAGE(BUF, KT) do {                                                           \
    const size_t _ko = (size_t)(KT) * 64;                                             \
    char* _d = smem + (BUF) * 12288 + tid * 16;                                       \
    __builtin_amdgcn_global_load_lds((GLOBAL_AS void*)(aStage + _ko),                 \
                                     (LDS_AS void*)(_d), 16, 0, 0);                   \
    __builtin_amdgcn_global_load_lds((GLOBAL_AS void*)(aStage + _ko + 12288),         \
                                     (LDS_AS void*)(_d + 2048), 16, 0, 0);            \
    __builtin_amdgcn_global_load_lds((GLOBAL_AS void*)(aStage + _ko + 24576),         \
                                     (LDS_AS void*)(_d + 4096), 16, 0, 0);            \
    __builtin_amdgcn_global_load_lds((GLOBAL_AS void*)(aStage + _ko + 36864),         \
                                     (LDS_AS void*)(_d + 6144), 16, 0, 0);            \
    __builtin_amdgcn_global_load_lds((GLOBAL_AS void*)(vStage + _ko),                 \
                                     (LDS_AS void*)(_d + 8192), 16, 0, 0);            \
    __builtin_amdgcn_global_load_lds((GLOBAL_AS void*)(vStage + _ko + 12288),         \
                                     (LDS_AS void*)(_d + 10240), 16, 0, 0);           \
  } while (0)

__global__ __launch_bounds__(128, 3) void gemm_max_kernel(
    const unsigned char* __restrict__ A, const unsigned char* __restrict__ V,
    float* __restrict__ rowquarter) {
    __shared__ __align__(1024) char smem[24576];

    const int tid = threadIdx.x;     // 0..127
    const int l   = tid & 63;
    const int wm  = tid >> 6;        // 0..1 : which 64-row half this wave owns
    const int lr  = l & 15;
    const int lg  = l >> 4;          // 0..3

    // O1 streaming block order + XCD swizzle (16384 blocks, %8==0 -> bijective)
    const int bx  = blockIdx.x;
    const int swz = (bx & 7) * 2048 + (bx >> 3);
    const int rowBlk = swz >> 7;     // 0..127
    const int colBlk = swz & 127;    // 0..127 (clip = colBlk>>2)
    const size_t aRow0 = (size_t)rowBlk * 128;
    const size_t vRow0 = (size_t)colBlk * 64;

    // staging source (frag-slot inverse). Row stride 384 B (fp4).
    const int rowT = 16 * (tid >> 6) + (tid & 15);      // + 32*q per chunk
    const int kbT  = ((tid >> 4) & 3) * 16;
    const unsigned char* aStage = A + (aRow0 + rowT) * 384 + kbT;
    const unsigned char* vStage = V + (vRow0 + rowT) * 384 + kbT;

    // reader bases (within buf): one b128 per frag at fi*1024 + l*16
    const int aBase = wm * 4096 + l * 16;   // + buf*12288 + mi*1024
    const int bBase = 8192 + l * 16;        // + buf*12288 + ni*1024

    f32x4 acc[4][4];
#pragma unroll
    for (int i = 0; i < 4; ++i)
#pragma unroll
        for (int j = 0; j < 4; ++j) {
            acc[i][j][0] = 0.0f; acc[i][j][1] = 0.0f;
            acc[i][j][2] = 0.0f; acc[i][j][3] = 0.0f;
        }

    // prologue: stage tiles 0 and 1 (12 loads/thread outstanding)
    STAGE(0, 0);
    STAGE(1, 1);

#pragma unroll 1
    for (int kt = 0; kt < 6; ++kt) {
        const int buf = kt & 1;
        // (1) own tile-kt loads landed (keep tile kt+1's 6 in flight)
        if (kt < 5) asm volatile("s_waitcnt vmcnt(6)" ::: "memory");
        else        asm volatile("s_waitcnt vmcnt(0)" ::: "memory");
        __builtin_amdgcn_sched_barrier(0);
        // (2) both waves reached (1) -> whole tile kt is in LDS
        __builtin_amdgcn_s_barrier();
        __builtin_amdgcn_sched_barrier(0);

        // (3) reads + MFMA (compiler inserts fine-grained lgkm waits)
        const char* aB = smem + buf * 12288 + aBase;
        const char* bB = smem + buf * 12288 + bBase;
        i32x8 fb[4];
#pragma unroll
        for (int ni = 0; ni < 4; ++ni) fb[ni] = rd_frag4(bB + ni * 1024);
#pragma unroll
        for (int mi = 0; mi < 4; ++mi) {
            const i32x8 fav = rd_frag4(aB + mi * 1024);
#pragma unroll
            for (int ni = 0; ni < 4; ++ni)
                acc[mi][ni] = __builtin_amdgcn_mfma_scale_f32_16x16x128_f8f6f4(
                    fav, fb[ni], acc[mi][ni], 4, 4, 0, 0x7F7F7F7F, 0, 0x7F7F7F7F);
        }

        // (4) both waves done reading buf (ds_reads complete before their MFMAs)
        __builtin_amdgcn_sched_barrier(0);
        __builtin_amdgcn_s_barrier();
        __builtin_amdgcn_sched_barrier(0);
        // (5) re-stage buf with tile kt+2 (lands >= 1 full iteration later)
        if (kt < 4) STAGE(buf, kt + 2);
    }

    // epilogue: fused row-max over this block's 64 visual cols; each wave owns
    // its 64 rows -> direct global write, no LDS staging.
    // C/D layout (16x16): col = lane&15, row = (lane>>4)*4 + reg (m89)
    float* outBase = rowquarter + (size_t)colBlk * 16384 + aRow0 + wm * 64;
#pragma unroll
    for (int mi = 0; mi < 4; ++mi) {
#pragma unroll
        for (int j = 0; j < 4; ++j) {
            float m = fmaxf(fmaxf(acc[mi][0][j], acc[mi][1][j]),
                            fmaxf(acc[mi][2][j], acc[mi][3][j]));
            m = fmaxf(m, __shfl_xor(m, 1, 64));
            m = fmaxf(m, __shfl_xor(m, 2, 64));
            m = fmaxf(m, __shfl_xor(m, 4, 64));
            m = fmaxf(m, __shfl_xor(m, 8, 64));
            if (lr == 0) outBase[mi * 16 + lg * 4 + j] = m;
        }
    }
}

// ---------- kernel 3: combine 4 quarter-clips (max) + mean over 512 rows ----------
// folds 1/temp (x10), 1/512 mean, and 1/1024 fp4 pre-scale compensation (32*32).
__global__ __launch_bounds__(256) void reduce_mean_kernel(const float* __restrict__ rq,
                                                          float* __restrict__ clip) {
    const int b = blockIdx.x >> 5;
    const int c = blockIdx.x & 31;
    const int t = threadIdx.x;
    const float* p = rq + (size_t)(c * 4) * 16384 + (size_t)b * 512;
    float s = 0.0f;
#pragma unroll
    for (int r = 0; r < 2; ++r) {
        const int o = t + r * 256;
        float m = fmaxf(fmaxf(p[o], p[o + 16384]),
                        fmaxf(p[o + 32768], p[o + 49152]));
        s += m;
    }
#pragma unroll
    for (int m = 1; m < 64; m <<= 1) s += __shfl_xor(s, m, 64);
    __shared__ float wsum[4];
    if ((t & 63) == 0) wsum[t >> 6] = s;
    __syncthreads();
    if (t == 0)
        clip[b * 32 + c] = (wsum[0] + wsum[1] + wsum[2] + wsum[3]) * (1.0f / (51.2f * 1024.0f));
}

// ---------- kernel 4: log-softmax both ways on 32x32 + scalar loss ----------
__global__ __launch_bounds__(1024) void finalize_kernel(const float* __restrict__ clip,
                                                        float* __restrict__ out) {
    __shared__ float cs[32][33];
    __shared__ float rlse[32], clse[32];
    const int t = threadIdx.x;
    const int b = t >> 5, c = t & 31;
    cs[b][c] = clip[b * 32 + c];
    __syncthreads();
    if (t < 32) {
        float mx = -1e30f;
        for (int j = 0; j < 32; ++j) mx = fmaxf(mx, cs[t][j]);
        float s = 0.0f;
        for (int j = 0; j < 32; ++j) s += expf(cs[t][j] - mx);
        rlse[t] = mx + logf(s);
    } else if (t < 64) {
        const int cc = t - 32;
        float mx = -1e30f;
        for (int j = 0; j < 32; ++j) mx = fmaxf(mx, cs[j][cc]);
        float s = 0.0f;
        for (int j = 0; j < 32; ++j) s += expf(cs[j][cc] - mx);
        clse[cc] = mx + logf(s);
    }
    __syncthreads();
    if (t == 0) {
        float L = 0.0f;
        for (int i = 0; i < 32; ++i)
            L += -0.5f * (2.0f * cs[i][i] - rlse[i] - clse[i]);
        out[0] = L * (1.0f / 32.0f);
    }
}

extern "C" void kernel_launch(void* const* d_in, const int* in_sizes, int n_in,
                              void* d_out, int out_size, void* d_ws, size_t ws_size,
                              hipStream_t stream) {
    const float* audio  = (const float*)d_in[0];   // (32, 512, 768) f32
    const float* visual = (const float*)d_in[1];   // (32, 256, 768) f32

    unsigned char* aN = (unsigned char*)d_ws;                   // 16384*384 fp4
    unsigned char* vN = aN + (size_t)16384 * 384;               // 8192*384 fp4
    float* rowquarter = (float*)(vN + (size_t)8192 * 384);      // 128*16384 f32
    float* clip       = rowquarter + (size_t)128 * 16384;       // 1024 f32
    float* out        = (float*)d_out;

    l2norm_fp4_kernel<<<6144, 256, 0, stream>>>(audio, visual, aN);
    gemm_max_kernel<<<16384, 128, 0, stream>>>(aN, vN, rowquarter);
    reduce_mean_kernel<<<1024, 256, 0, stream>>>(rowquarter, clip);
    finalize_kernel<<<1, 1024, 0, stream>>>(clip, out);
}

// Round 21
// 116.601 us; speedup vs baseline: 1.3721x; 1.3721x over previous
//
#include <hip/hip_runtime.h>

#define GLOBAL_AS __attribute__((address_space(1)))
#define LDS_AS    __attribute__((address_space(3)))

typedef int   i32x4  __attribute__((ext_vector_type(4)));
typedef int   i32x8  __attribute__((ext_vector_type(8)));
typedef float f32x4  __attribute__((ext_vector_type(4)));

// ---------- fp4 e2m1 encode: values {0,.5,1,1.5,2,3,4,6}, round-to-nearest ----------
__device__ __forceinline__ unsigned int fp4_nib(float v) {
    float a = fabsf(v);
    unsigned int m;
    if      (a < 0.25f) m = 0;
    else if (a < 0.75f) m = 1;
    else if (a < 1.25f) m = 2;
    else if (a < 1.75f) m = 3;
    else if (a < 2.5f)  m = 4;
    else if (a < 3.5f)  m = 5;
    else if (a < 5.0f)  m = 6;
    else                m = 7;
    return m | (v < 0.0f ? 8u : 0u);
}

// ---------- kernel 1: fused L2 normalize -> fp4 of (x * 32 / ||row||) ----------
// out rows: 768 elts = 384 B (2 elts/byte, elt 2i = low nibble).
__global__ __launch_bounds__(256) void l2norm_fp4_kernel(const float* __restrict__ audio,
                                                         const float* __restrict__ visual,
                                                         unsigned char* __restrict__ out) {
    const int gw = blockIdx.x * 4 + (threadIdx.x >> 6);  // global row 0..24575
    const int l  = threadIdx.x & 63;
    const float* src = (gw < 16384) ? (audio + (size_t)gw * 768)
                                    : (visual + ((size_t)gw - 16384) * 768);
    const float4* p = (const float4*)src;
    float4 a = p[l], b = p[l + 64], c = p[l + 128];
    float ss = a.x * a.x + a.y * a.y + a.z * a.z + a.w * a.w
             + b.x * b.x + b.y * b.y + b.z * b.z + b.w * b.w
             + c.x * c.x + c.y * c.y + c.z * c.z + c.w * c.w;
#pragma unroll
    for (int m = 1; m < 64; m <<= 1) ss += __shfl_xor(ss, m, 64);
    const float s = 32.0f / fmaxf(sqrtf(ss), 1e-12f);
    unsigned short* o = (unsigned short*)(out + (size_t)gw * 384);
    unsigned short u0 = (unsigned short)(fp4_nib(a.x * s) | (fp4_nib(a.y * s) << 4) |
                                         (fp4_nib(a.z * s) << 8) | (fp4_nib(a.w * s) << 12));
    unsigned short u1 = (unsigned short)(fp4_nib(b.x * s) | (fp4_nib(b.y * s) << 4) |
                                         (fp4_nib(b.z * s) << 8) | (fp4_nib(b.w * s) << 12));
    unsigned short u2 = (unsigned short)(fp4_nib(c.x * s) | (fp4_nib(c.y * s) << 4) |
                                         (fp4_nib(c.z * s) << 8) | (fp4_nib(c.w * s) << 12));
    o[l] = u0; o[l + 64] = u1; o[l + 128] = u2;
}

// ---------- kernel 2: 128x128-tile MX-fp4 GEMM (mfma_scale 16x16x128, fmt=4) -------
// R18/R19 verified base (counted-vmcnt double-buffer, GEMM 103.7 us) with ONE
// change: __launch_bounds__(256, 4). Register arithmetic: measured demand =
// 64 VGPR + 64 AGPR acc = 128 unified; (256,4) cap = 512/4 = 128 — exactly fits
// (R15's (256,6) cap 85 spilled; R5's 128-cap vs ~176 demand spilled). 4 blocks/CU
// -> 4 independent wave-streams/SIMD to fill the ~60%-idle issue windows of the
// 2-phase structure (nothing saturated: MFMA 27%, LDS ~35%, VALU 33%).
// TRIPWIRE: if WRITE_SIZE blows past ~10 MB -> spill -> revert to (256,3).
// Schedule per K-tile kt (buf=kt&1): vmcnt(4) [kt landed, kt+1 in flight] ->
// raw s_barrier -> ds_reads + 16 MFMA -> raw s_barrier -> STAGE(buf, kt+2).
// No vmcnt(0) drain in the main loop; stage->use distance = 2 iterations.
// Frag-slot layout: granule s = fi*64 + lane holds (row = fi*16 + (lane&15),
// K-bytes (lane>>4)*16 .. +15) -> ONE lane-linear ds_read_b128/frag (0 conflicts);
// stage dest linear tid*16; source row = q*64+(tid>>6)*16+(tid&15),
// kb = ((tid>>4)&3)*16 (wave = 16 rows x contiguous 64 B, fully coalesced).
// MFMA: cbsz=4, blgp=4 (FP4), payload in regs [0:3] (upper undef, R19-verified).

__device__ __forceinline__ i32x8 rd_frag4(const char* p) {
    i32x4 d = *(const i32x4*)(p);
    // upper 4 regs UNDEF: fp4 MFMA (cbsz=blgp=4) consumes only regs [0:3]
    return __builtin_shufflevector(d, d, 0, 1, 2, 3, -1, -1, -1, -1);
}

#define STAGE(BUF, KT) do {                                                           \
    const size_t _ko = (size_t)(KT) * 64;                                             \
    char* _d = smem + (BUF) * 16384 + tid * 16;                                       \
    __builtin_amdgcn_global_load_lds((GLOBAL_AS void*)(aStage + _ko),                 \
                                     (LDS_AS void*)(_d), 16, 0, 0);                   \
    __builtin_amdgcn_global_load_lds((GLOBAL_AS void*)(aStage + _ko + 24576),         \
                                     (LDS_AS void*)(_d + 4096), 16, 0, 0);            \
    __builtin_amdgcn_global_load_lds((GLOBAL_AS void*)(vStage + _ko),                 \
                                     (LDS_AS void*)(_d + 8192), 16, 0, 0);            \
    __builtin_amdgcn_global_load_lds((GLOBAL_AS void*)(vStage + _ko + 24576),         \
                                     (LDS_AS void*)(_d + 12288), 16, 0, 0);           \
  } while (0)

__global__ __launch_bounds__(256, 4) void gemm_max_kernel(
    const unsigned char* __restrict__ A, const unsigned char* __restrict__ V,
    float* __restrict__ rowhalf) {
    __shared__ __align__(1024) char smem[32768];

    const int tid = threadIdx.x;
    const int l   = tid & 63;
    const int wid = tid >> 6;
    const int wm  = wid >> 1;      // 0..1 : 64-row half of A tile
    const int wn  = wid & 1;       // 0..1 : 64-col half of B tile
    const int lr  = l & 15;
    const int lg  = l >> 4;        // 0..3

    // O1 streaming block order (R9-measured fastest; O2 L2-sharing = +33 us)
    const int bx  = blockIdx.x;                   // 8192 blocks, %8==0 -> bijective
    const int swz = (bx & 7) * 1024 + (bx >> 3);  // XCD-aware swizzle
    const int rowBlk = swz >> 6;                  // 0..127
    const int colBlk = swz & 63;                  // 0..63 (clip = colBlk>>1)
    const size_t aRow0 = (size_t)rowBlk * 128;
    const size_t vRow0 = (size_t)colBlk * 128;

    // staging source (frag-slot inverse; see header). Row stride 384 B (fp4).
    const int rowT = (tid >> 6) * 16 + (tid & 15);      // 0..31 (q adds 64)
    const int kbT  = ((tid >> 4) & 3) * 16;             // 0..48
    const unsigned char* aStage = A + (aRow0 + rowT) * 384 + kbT;
    const unsigned char* vStage = V + (vRow0 + rowT) * 384 + kbT;

    // reader bases (within buf): one b128 per frag at fi*1024 + l*16
    const int aBase = wm * 4096 + l * 16;           // + buf*16384 + mi*1024
    const int bBase = 8192 + wn * 4096 + l * 16;    // + buf*16384 + ni*1024

    f32x4 acc[4][4];
#pragma unroll
    for (int i = 0; i < 4; ++i)
#pragma unroll
        for (int j = 0; j < 4; ++j) {
            acc[i][j][0] = 0.0f; acc[i][j][1] = 0.0f;
            acc[i][j][2] = 0.0f; acc[i][j][3] = 0.0f;
        }

    // prologue: stage tiles 0 and 1 (8 loads/thread outstanding)
    STAGE(0, 0);
    STAGE(1, 1);

#pragma unroll 1
    for (int kt = 0; kt < 6; ++kt) {
        const int buf = kt & 1;
        // (1) own tile-kt loads landed (keep tile kt+1's 4 in flight)
        if (kt < 5) asm volatile("s_waitcnt vmcnt(4)" ::: "memory");
        else        asm volatile("s_waitcnt vmcnt(0)" ::: "memory");
        __builtin_amdgcn_sched_barrier(0);
        // (2) all waves reached (1) -> whole tile kt is in LDS
        __builtin_amdgcn_s_barrier();
        __builtin_amdgcn_sched_barrier(0);

        // (3) reads + MFMA (compiler inserts fine-grained lgkm waits)
        const char* aB = smem + buf * 16384 + aBase;
        const char* bB = smem + buf * 16384 + bBase;
        i32x8 fb[4];
#pragma unroll
        for (int ni = 0; ni < 4; ++ni) fb[ni] = rd_frag4(bB + ni * 1024);
#pragma unroll
        for (int mi = 0; mi < 4; ++mi) {
            const i32x8 fav = rd_frag4(aB + mi * 1024);
#pragma unroll
            for (int ni = 0; ni < 4; ++ni)
                acc[mi][ni] = __builtin_amdgcn_mfma_scale_f32_16x16x128_f8f6f4(
                    fav, fb[ni], acc[mi][ni], 4, 4, 0, 0x7F7F7F7F, 0, 0x7F7F7F7F);
        }

        // (4) all waves done reading buf (ds_reads complete before their MFMAs)
        __builtin_amdgcn_sched_barrier(0);
        __builtin_amdgcn_s_barrier();
        __builtin_amdgcn_sched_barrier(0);
        // (5) re-stage buf with tile kt+2 (lands >= 1 full iteration later)
        if (kt < 4) STAGE(buf, kt + 2);
    }

    // epilogue: fused row-max over this block's 128 visual cols.
    // C/D layout (16x16): col = lane&15, row = (lane>>4)*4 + reg (m89; shape-determined)
    float* pm = (float*)smem;  // [128 rows][2 wn]; buf0 last read kt=4, certified
#pragma unroll
    for (int mi = 0; mi < 4; ++mi) {
#pragma unroll
        for (int j = 0; j < 4; ++j) {
            float m = fmaxf(fmaxf(acc[mi][0][j], acc[mi][1][j]),
                            fmaxf(acc[mi][2][j], acc[mi][3][j]));
            m = fmaxf(m, __shfl_xor(m, 1, 64));
            m = fmaxf(m, __shfl_xor(m, 2, 64));
            m = fmaxf(m, __shfl_xor(m, 4, 64));
            m = fmaxf(m, __shfl_xor(m, 8, 64));
            if (lr == 0) {
                const int row = wm * 64 + mi * 16 + lg * 4 + j;
                pm[row * 2 + wn] = m;
            }
        }
    }
    __syncthreads();
    if (tid < 128) {
        float m = fmaxf(pm[tid * 2], pm[tid * 2 + 1]);
        rowhalf[(size_t)colBlk * 16384 + aRow0 + tid] = m;
    }
}

// ---------- kernel 3: combine halves (max) + mean over 512 rows -> clip_sims ----------
// folds 1/temp (x10), 1/512 mean, and 1/1024 fp4 pre-scale compensation (32*32).
__global__ __launch_bounds__(256) void reduce_mean_kernel(const float* __restrict__ rh,
                                                          float* __restrict__ clip) {
    const int b = blockIdx.x >> 5;
    const int c = blockIdx.x & 31;
    const int t = threadIdx.x;
    const float* p0 = rh + (size_t)(c * 2) * 16384 + (size_t)b * 512;
    const float* p1 = p0 + 16384;
    float s = fmaxf(p0[t], p1[t]) + fmaxf(p0[t + 256], p1[t + 256]);
#pragma unroll
    for (int m = 1; m < 64; m <<= 1) s += __shfl_xor(s, m, 64);
    __shared__ float wsum[4];
    if ((t & 63) == 0) wsum[t >> 6] = s;
    __syncthreads();
    if (t == 0)
        clip[b * 32 + c] = (wsum[0] + wsum[1] + wsum[2] + wsum[3]) * (1.0f / (51.2f * 1024.0f));
}

// ---------- kernel 4: log-softmax both ways on 32x32 + scalar loss ----------
__global__ __launch_bounds__(1024) void finalize_kernel(const float* __restrict__ clip,
                                                        float* __restrict__ out) {
    __shared__ float cs[32][33];
    __shared__ float rlse[32], clse[32];
    const int t = threadIdx.x;
    const int b = t >> 5, c = t & 31;
    cs[b][c] = clip[b * 32 + c];
    __syncthreads();
    if (t < 32) {
        float mx = -1e30f;
        for (int j = 0; j < 32; ++j) mx = fmaxf(mx, cs[t][j]);
        float s = 0.0f;
        for (int j = 0; j < 32; ++j) s += expf(cs[t][j] - mx);
        rlse[t] = mx + logf(s);
    } else if (t < 64) {
        const int cc = t - 32;
        float mx = -1e30f;
        for (int j = 0; j < 32; ++j) mx = fmaxf(mx, cs[j][cc]);
        float s = 0.0f;
        for (int j = 0; j < 32; ++j) s += expf(cs[j][cc] - mx);
        clse[cc] = mx + logf(s);
    }
    __syncthreads();
    if (t == 0) {
        float L = 0.0f;
        for (int i = 0; i < 32; ++i)
            L += -0.5f * (2.0f * cs[i][i] - rlse[i] - clse[i]);
        out[0] = L * (1.0f / 32.0f);
    }
}

extern "C" void kernel_launch(void* const* d_in, const int* in_sizes, int n_in,
                              void* d_out, int out_size, void* d_ws, size_t ws_size,
                              hipStream_t stream) {
    const float* audio  = (const float*)d_in[0];   // (32, 512, 768) f32
    const float* visual = (const float*)d_in[1];   // (32, 256, 768) f32

    unsigned char* aN = (unsigned char*)d_ws;                   // 16384*384 fp4
    unsigned char* vN = aN + (size_t)16384 * 384;               // 8192*384 fp4
    float* rowhalf = (float*)(vN + (size_t)8192 * 384);         // 64*16384 f32
    float* clip    = rowhalf + (size_t)64 * 16384;              // 1024 f32
    float* out     = (float*)d_out;

    l2norm_fp4_kernel<<<6144, 256, 0, stream>>>(audio, visual, aN);
    gemm_max_kernel<<<8192, 256, 0, stream>>>(aN, vN, rowhalf);
    reduce_mean_kernel<<<1024, 256, 0, stream>>>(rowhalf, clip);
    finalize_kernel<<<1, 1024, 0, stream>>>(clip, out);
}